// Round 4
// baseline (1444.180 us; speedup 1.0000x reference)
//
#include <hip/hip_runtime.h>
#include <hip/hip_bf16.h>
#include <stdint.h>

#define MROWS 16384   // B*S
#define KDIM  2048
#define NDIM  2048
#define LEAFD 13
#define RANKD 4

typedef __bf16 bf16x8 __attribute__((ext_vector_type(8)));
typedef float  f32x4  __attribute__((ext_vector_type(4)));

// ---------------------------------------------------------------------------
// Kernel 1: w_bf[o,i] = bf16( weight[o,i] + sum_r L0[r,o2,i2]*L1[r,o1,i1]*L2[r,o0,i0] )
// ---------------------------------------------------------------------------
__global__ void build_w_kernel(const float* __restrict__ weight,
                               const float* __restrict__ leaf,
                               __hip_bfloat16* __restrict__ wbf) {
    __shared__ float ll[3 * RANKD * LEAFD * LEAFD];
    for (int t = threadIdx.x; t < 3 * RANKD * LEAFD * LEAFD; t += blockDim.x)
        ll[t] = leaf[t];
    __syncthreads();
    int idx = blockIdx.x * blockDim.x + threadIdx.x;
    if (idx >= NDIM * KDIM) return;
    int o = idx / KDIM, i = idx % KDIM;
    int o2 = o / 169, o1 = (o / 13) % 13, o0 = o % 13;
    int i2 = i / 169, i1 = (i / 13) % 13, i0 = i % 13;
    float d = 0.f;
#pragma unroll
    for (int r = 0; r < RANKD; ++r) {
        float a = ll[( r            * LEAFD + o2) * LEAFD + i2];
        float b = ll[((RANKD   + r) * LEAFD + o1) * LEAFD + i1];
        float c = ll[((2*RANKD + r) * LEAFD + o0) * LEAFD + i0];
        d += a * b * c;
    }
    wbf[idx] = __float2bfloat16(weight[idx] + d);
}

// ---------------------------------------------------------------------------
// Kernel 2: fp32 -> bf16 conversion of activations (8 floats/thread)
// ---------------------------------------------------------------------------
__global__ void cvt_kernel(const float* __restrict__ x,
                           __hip_bfloat16* __restrict__ xb, int n) {
    long stride = (long)gridDim.x * blockDim.x * 8;
    for (long idx = ((long)blockIdx.x * blockDim.x + threadIdx.x) * 8; idx < n; idx += stride) {
        float4 v0 = *reinterpret_cast<const float4*>(x + idx);
        float4 v1 = *reinterpret_cast<const float4*>(x + idx + 4);
        __hip_bfloat16 tmp[8];
        tmp[0] = __float2bfloat16(v0.x); tmp[1] = __float2bfloat16(v0.y);
        tmp[2] = __float2bfloat16(v0.z); tmp[3] = __float2bfloat16(v0.w);
        tmp[4] = __float2bfloat16(v1.x); tmp[5] = __float2bfloat16(v1.y);
        tmp[6] = __float2bfloat16(v1.z); tmp[7] = __float2bfloat16(v1.w);
        *reinterpret_cast<uint4*>(xb + idx) = *reinterpret_cast<const uint4*>(tmp);
    }
}

// ---------------------------------------------------------------------------
// Kernel 3: 256x256 tile, BK=32, 2-phase/K-tile GEMM, 2 blocks/CU (TLP overlap).
// 512 threads = 8 waves (2M x 4N); per-wave output 128x64; bf16 in, fp32 out.
// LDS 64 KiB: 2 bufs x {A slot 16KB, B slot 16KB}; slot = 256 rows x 32 k.
// During tile t (buf c): p0 stages A(t+1)->buf c^1, p1 stages B(t+1); single
// vmcnt(0) AFTER p1's MFMA (max slack). Residual latency is hidden by the
// co-resident second block (m114 co-scheduling), not by queue depth.
// Swizzle: byte involution a ^= ((a>>7)&7)<<4 on global SOURCE of
// global_load_lds (linear LDS dest) and on the ds_read address (both sides).
// ---------------------------------------------------------------------------

__device__ __forceinline__ void gload16(const __hip_bfloat16* g, char* l) {
    __builtin_amdgcn_global_load_lds((const __attribute__((address_space(1))) void*)g,
                                     (__attribute__((address_space(3))) void*)l,
                                     16, 0, 0);
}

#define STAGE(base, kb, bufi, slot) do {                                          \
    gload16((base) + (kb) + gOff0, smemc + (bufi)*32768 + (slot)*16384 + lOff0);  \
    gload16((base) + (kb) + gOff1, smemc + (bufi)*32768 + (slot)*16384 + lOff1);  \
} while (0)

#define LOAD_A(mh, bufc)                                                      \
    af0 = *(const bf16x8*)(smemc + (bufc)*32768 + offA[(mh)*4+0]);            \
    af1 = *(const bf16x8*)(smemc + (bufc)*32768 + offA[(mh)*4+1]);            \
    af2 = *(const bf16x8*)(smemc + (bufc)*32768 + offA[(mh)*4+2]);            \
    af3 = *(const bf16x8*)(smemc + (bufc)*32768 + offA[(mh)*4+3]);

#define LOAD_B(bufc)                                                          \
    bf0 = *(const bf16x8*)(smemc + (bufc)*32768 + 16384 + offB[0]);           \
    bf1 = *(const bf16x8*)(smemc + (bufc)*32768 + 16384 + offB[1]);           \
    bf2 = *(const bf16x8*)(smemc + (bufc)*32768 + 16384 + offB[2]);           \
    bf3 = *(const bf16x8*)(smemc + (bufc)*32768 + 16384 + offB[3]);

#define MFMA_Q(mh) do {                                                                   \
    acc[(mh)*4+0][0] = __builtin_amdgcn_mfma_f32_16x16x32_bf16(af0, bf0, acc[(mh)*4+0][0], 0,0,0); \
    acc[(mh)*4+1][0] = __builtin_amdgcn_mfma_f32_16x16x32_bf16(af1, bf0, acc[(mh)*4+1][0], 0,0,0); \
    acc[(mh)*4+2][0] = __builtin_amdgcn_mfma_f32_16x16x32_bf16(af2, bf0, acc[(mh)*4+2][0], 0,0,0); \
    acc[(mh)*4+3][0] = __builtin_amdgcn_mfma_f32_16x16x32_bf16(af3, bf0, acc[(mh)*4+3][0], 0,0,0); \
    acc[(mh)*4+0][1] = __builtin_amdgcn_mfma_f32_16x16x32_bf16(af0, bf1, acc[(mh)*4+0][1], 0,0,0); \
    acc[(mh)*4+1][1] = __builtin_amdgcn_mfma_f32_16x16x32_bf16(af1, bf1, acc[(mh)*4+1][1], 0,0,0); \
    acc[(mh)*4+2][1] = __builtin_amdgcn_mfma_f32_16x16x32_bf16(af2, bf1, acc[(mh)*4+2][1], 0,0,0); \
    acc[(mh)*4+3][1] = __builtin_amdgcn_mfma_f32_16x16x32_bf16(af3, bf1, acc[(mh)*4+3][1], 0,0,0); \
    acc[(mh)*4+0][2] = __builtin_amdgcn_mfma_f32_16x16x32_bf16(af0, bf2, acc[(mh)*4+0][2], 0,0,0); \
    acc[(mh)*4+1][2] = __builtin_amdgcn_mfma_f32_16x16x32_bf16(af1, bf2, acc[(mh)*4+1][2], 0,0,0); \
    acc[(mh)*4+2][2] = __builtin_amdgcn_mfma_f32_16x16x32_bf16(af2, bf2, acc[(mh)*4+2][2], 0,0,0); \
    acc[(mh)*4+3][2] = __builtin_amdgcn_mfma_f32_16x16x32_bf16(af3, bf2, acc[(mh)*4+3][2], 0,0,0); \
    acc[(mh)*4+0][3] = __builtin_amdgcn_mfma_f32_16x16x32_bf16(af0, bf3, acc[(mh)*4+0][3], 0,0,0); \
    acc[(mh)*4+1][3] = __builtin_amdgcn_mfma_f32_16x16x32_bf16(af1, bf3, acc[(mh)*4+1][3], 0,0,0); \
    acc[(mh)*4+2][3] = __builtin_amdgcn_mfma_f32_16x16x32_bf16(af2, bf3, acc[(mh)*4+2][3], 0,0,0); \
    acc[(mh)*4+3][3] = __builtin_amdgcn_mfma_f32_16x16x32_bf16(af3, bf3, acc[(mh)*4+3][3], 0,0,0); \
} while (0)

#define BARRIER_IN do {                                     \
    __builtin_amdgcn_sched_barrier(0);                      \
    __builtin_amdgcn_s_barrier();                           \
    asm volatile("s_waitcnt lgkmcnt(0)" ::: "memory");      \
    __builtin_amdgcn_sched_barrier(0);                      \
    __builtin_amdgcn_s_setprio(1);                          \
} while (0)

#define BARRIER_OUT do {                                    \
    __builtin_amdgcn_s_setprio(0);                          \
    __builtin_amdgcn_sched_barrier(0);                      \
    __builtin_amdgcn_s_barrier();                           \
    __builtin_amdgcn_sched_barrier(0);                      \
} while (0)

#define WAIT0 asm volatile("s_waitcnt vmcnt(0)" ::: "memory")
#define WNONE do {} while (0)

// One K-tile (K=32) = 2 phases. Stage t+1 into buf^1 during tile t.
// Liveness: all reads of buf^1 (tile t-1) complete before any wave passes
// p1(t-1)'s closing barrier; stages issue after it. vmcnt(0) sits after
// p1's MFMA so the t+1 loads get ~1.5 phases of slack before the wait.
#define KTILE32(t, bufc, SG, WT) do {                               \
    /* p0 */                                                        \
    LOAD_B(bufc); LOAD_A(0, bufc);                                  \
    if (SG) STAGE(Abase, ((t)+1)*32, (bufc)^1, 0);                  \
    BARRIER_IN; MFMA_Q(0); BARRIER_OUT;                             \
    /* p1 */                                                        \
    LOAD_A(1, bufc);                                                \
    if (SG) STAGE(Bbase, ((t)+1)*32, (bufc)^1, 1);                  \
    BARRIER_IN; MFMA_Q(1);                                          \
    WT;                                                             \
    BARRIER_OUT;                                                    \
} while (0)

__global__ __launch_bounds__(512, 4) void gemm2_kernel(const __hip_bfloat16* __restrict__ A,
                                                       const __hip_bfloat16* __restrict__ Wb,
                                                       const float* __restrict__ bias,
                                                       float* __restrict__ C) {
    __shared__ __align__(16) __hip_bfloat16 smem[2][2][8192];  // 64 KiB -> 2 blocks/CU
    char* smemc = (char*)&smem[0][0][0];

    const int tid  = threadIdx.x;
    const int lane = tid & 63;
    const int wid  = tid >> 6;        // 0..7
    const int wr   = wid >> 2;        // 0..1  (M half)
    const int wc   = wid & 3;         // 0..3  (N quarter)

    // T1: XCD-aware swizzle (nwg=512, 512%8==0 -> bijective).
    const int bid = blockIdx.x;
    const int swz = (bid & 7) * 64 + (bid >> 3);
    const int bn  = swz >> 6;         // 0..7
    const int bm  = swz & 63;         // 0..63

    const __hip_bfloat16* Abase = A  + (size_t)bm * 256 * KDIM;
    const __hip_bfloat16* Bbase = Wb + (size_t)bn * 256 * KDIM;

    // --- staging source offsets (inverse-swizzled global, linear LDS dest) ---
    const int c0  = wid * 64 + lane;          // chunk 0..511
    const int c1  = 512 + wid * 64 + lane;    // chunk 512..1023
    const int cs0 = c0 ^ ((c0 >> 3) & 7);
    const int cs1 = c1 ^ ((c1 >> 3) & 7);
    const int gOff0 = (cs0 >> 2) * KDIM + (cs0 & 3) * 8;   // elements
    const int gOff1 = (cs1 >> 2) * KDIM + (cs1 & 3) * 8;
    const int lOff0 = wid * 1024;                          // bytes (wave-uniform)
    const int lOff1 = 8192 + wid * 1024;

    // --- swizzled ds_read byte offsets within a 16 KB slot ---
    const int rsel = lane & 15;
    const int kby  = (lane >> 4) * 16;
    int offA[8], offB[4];
#pragma unroll
    for (int m = 0; m < 8; ++m) {
        int a = (wr * 128 + m * 16 + rsel) * 64 + kby;
        offA[m] = a ^ (((a >> 7) & 7) << 4);
    }
#pragma unroll
    for (int n = 0; n < 4; ++n) {
        int a = (wc * 64 + n * 16 + rsel) * 64 + kby;
        offB[n] = a ^ (((a >> 7) & 7) << 4);
    }

    f32x4 acc[8][4];
#pragma unroll
    for (int m = 0; m < 8; ++m)
#pragma unroll
        for (int n = 0; n < 4; ++n)
            acc[m][n] = (f32x4){0.f, 0.f, 0.f, 0.f};

    bf16x8 af0, af1, af2, af3, bf0, bf1, bf2, bf3;

    // --- prologue: stage tile0 (A,B) into buf0 ---
    STAGE(Abase, 0, 0, 0);
    STAGE(Bbase, 0, 0, 1);
    WAIT0;
    __builtin_amdgcn_sched_barrier(0);
    __builtin_amdgcn_s_barrier();
    __builtin_amdgcn_sched_barrier(0);

    // --- main loop: KDIM/32 = 64 K-tiles ---
    for (int t = 0; t < 62; t += 2) {
        KTILE32(t,     0, 1, WAIT0);
        KTILE32(t + 1, 1, 1, WAIT0);
    }
    KTILE32(62, 0, 1, WAIT0);
    KTILE32(63, 1, 0, WNONE);

    // --- epilogue: C/D layout col = lane&15, row = (lane>>4)*4 + r ---
    const int col0 = lane & 15;
    const int r0   = (lane >> 4) * 4;
#pragma unroll
    for (int n = 0; n < 4; ++n) {
        const int cg = bn * 256 + wc * 64 + n * 16 + col0;
        const float bv = bias[cg];
#pragma unroll
        for (int m = 0; m < 8; ++m) {
            const size_t rg = (size_t)bm * 256 + wr * 128 + m * 16 + r0;
#pragma unroll
            for (int r = 0; r < 4; ++r)
                C[(rg + r) * NDIM + cg] = acc[m][n][r] + bv;
        }
    }
}

// ---------------------------------------------------------------------------
// Fallback: naive fused fp32 GEMM (only if workspace too small).
// ---------------------------------------------------------------------------
__global__ void naive_kernel(const float* __restrict__ x,
                             const float* __restrict__ leaf,
                             const float* __restrict__ W,
                             const float* __restrict__ bias,
                             float* __restrict__ out) {
    long idx = (long)blockIdx.x * blockDim.x + threadIdx.x;
    if (idx >= (long)MROWS * NDIM) return;
    int  o = (int)(idx % NDIM);
    long m = idx / NDIM;
    int o2 = o / 169, o1 = (o / 13) % 13, o0 = o % 13;
    float acc = 0.f;
    for (int i = 0; i < KDIM; ++i) {
        int i2 = i / 169, i1 = (i / 13) % 13, i0 = i % 13;
        float d = 0.f;
#pragma unroll
        for (int r = 0; r < RANKD; ++r)
            d += leaf[( r     * LEAFD + o2) * LEAFD + i2]
               * leaf[((4 + r) * LEAFD + o1) * LEAFD + i1]
               * leaf[((8 + r) * LEAFD + o0) * LEAFD + i0];
        acc += x[m * KDIM + i] * (W[(long)o * KDIM + i] + d);
    }
    out[idx] = acc + bias[o];
}

// ---------------------------------------------------------------------------
extern "C" void kernel_launch(void* const* d_in, const int* in_sizes, int n_in,
                              void* d_out, int out_size, void* d_ws, size_t ws_size,
                              hipStream_t stream) {
    const float* x      = (const float*)d_in[0];
    const float* leaf   = (const float*)d_in[1];
    const float* weight = (const float*)d_in[2];
    const float* bias   = (const float*)d_in[3];
    float* out = (float*)d_out;

    const size_t needA = (size_t)MROWS * KDIM * sizeof(__hip_bfloat16);  // 64 MiB
    const size_t needW = (size_t)NDIM  * KDIM * sizeof(__hip_bfloat16);  // 8 MiB

    if (ws_size >= needA + needW) {
        __hip_bfloat16* xb = (__hip_bfloat16*)d_ws;
        __hip_bfloat16* wb = (__hip_bfloat16*)((char*)d_ws + needA);
        build_w_kernel<<<(NDIM * KDIM + 255) / 256, 256, 0, stream>>>(weight, leaf, wb);
        cvt_kernel<<<2048, 256, 0, stream>>>(x, xb, MROWS * KDIM);
        gemm2_kernel<<<(MROWS / 256) * (NDIM / 256), 512, 0, stream>>>(xb, wb, bias, out);
    } else {
        long total = (long)MROWS * NDIM;
        naive_kernel<<<(int)((total + 255) / 256), 256, 0, stream>>>(x, leaf, weight, bias, out);
    }
}

// Round 5
// 209.670 us; speedup vs baseline: 6.8879x; 6.8879x over previous
//
#include <hip/hip_runtime.h>
#include <hip/hip_bf16.h>
#include <stdint.h>

#define MROWS 16384   // B*S
#define KDIM  2048
#define NDIM  2048
#define LEAFD 13
#define RANKD 4

typedef __bf16 bf16x8 __attribute__((ext_vector_type(8)));
typedef float  f32x4  __attribute__((ext_vector_type(4)));
typedef float  f32x16 __attribute__((ext_vector_type(16)));

// ---------------------------------------------------------------------------
// Kernel 1: w_bf[o,i] = bf16( weight[o,i] + sum_r L0[r,o2,i2]*L1[r,o1,i1]*L2[r,o0,i0] )
// ---------------------------------------------------------------------------
__global__ void build_w_kernel(const float* __restrict__ weight,
                               const float* __restrict__ leaf,
                               __hip_bfloat16* __restrict__ wbf) {
    __shared__ float ll[3 * RANKD * LEAFD * LEAFD];
    for (int t = threadIdx.x; t < 3 * RANKD * LEAFD * LEAFD; t += blockDim.x)
        ll[t] = leaf[t];
    __syncthreads();
    int idx = blockIdx.x * blockDim.x + threadIdx.x;
    if (idx >= NDIM * KDIM) return;
    int o = idx / KDIM, i = idx % KDIM;
    int o2 = o / 169, o1 = (o / 13) % 13, o0 = o % 13;
    int i2 = i / 169, i1 = (i / 13) % 13, i0 = i % 13;
    float d = 0.f;
#pragma unroll
    for (int r = 0; r < RANKD; ++r) {
        float a = ll[( r            * LEAFD + o2) * LEAFD + i2];
        float b = ll[((RANKD   + r) * LEAFD + o1) * LEAFD + i1];
        float c = ll[((2*RANKD + r) * LEAFD + o0) * LEAFD + i0];
        d += a * b * c;
    }
    wbf[idx] = __float2bfloat16(weight[idx] + d);
}

// ---------------------------------------------------------------------------
// Kernel 2: fp32 -> bf16 conversion of activations (8 floats/thread)
// ---------------------------------------------------------------------------
__global__ void cvt_kernel(const float* __restrict__ x,
                           __hip_bfloat16* __restrict__ xb, int n) {
    long stride = (long)gridDim.x * blockDim.x * 8;
    for (long idx = ((long)blockIdx.x * blockDim.x + threadIdx.x) * 8; idx < n; idx += stride) {
        float4 v0 = *reinterpret_cast<const float4*>(x + idx);
        float4 v1 = *reinterpret_cast<const float4*>(x + idx + 4);
        __hip_bfloat16 tmp[8];
        tmp[0] = __float2bfloat16(v0.x); tmp[1] = __float2bfloat16(v0.y);
        tmp[2] = __float2bfloat16(v0.z); tmp[3] = __float2bfloat16(v0.w);
        tmp[4] = __float2bfloat16(v1.x); tmp[5] = __float2bfloat16(v1.y);
        tmp[6] = __float2bfloat16(v1.z); tmp[7] = __float2bfloat16(v1.w);
        *reinterpret_cast<uint4*>(xb + idx) = *reinterpret_cast<const uint4*>(tmp);
    }
}

// ---------------------------------------------------------------------------
// Kernel 3: 256x256 tile, BK=32, 32x32x16 MFMA, triple-buffered LDS (96 KB).
// 512 threads = 8 waves (2M x 4N); per-wave output 128x64 = 4x2 frags of 32x32.
// One barrier-pair per K-tile: {6 ds_read(k0) | stage tile t+2 (4 gload) |
// barrier, lgkm0, setprio, 8 MFMA(k0), 6 ds_read(k1), lgkm0, 8 MFMA(k1),
// vmcnt(4), barrier}. Stage of t+2 during t -> vmcnt wait covers loads issued
// a full tile (~2 windows) earlier. Swizzle: a ^= ((a>>7)&7)<<4 on both the
// global SOURCE of global_load_lds (linear LDS dest) and the ds_read address.
// ---------------------------------------------------------------------------

__device__ __forceinline__ void gload16(const __hip_bfloat16* g, char* l) {
    __builtin_amdgcn_global_load_lds((const __attribute__((address_space(1))) void*)g,
                                     (__attribute__((address_space(3))) void*)l,
                                     16, 0, 0);
}

#define STAGE(base, kb, bufi, slot) do {                                          \
    gload16((base) + (kb) + gOff0, smemc + (bufi)*32768 + (slot)*16384 + lOff0);  \
    gload16((base) + (kb) + gOff1, smemc + (bufi)*32768 + (slot)*16384 + lOff1);  \
} while (0)

// 6 x ds_read_b128: A frags (4 x 32 rows) + B frags (2 x 32 cols), one kstep.
#define LOADK(ks, bufc)                                                       \
    a0 = *(const bf16x8*)(smemc + (bufc)*32768 + offA[0][ks]);                \
    a1 = *(const bf16x8*)(smemc + (bufc)*32768 + offA[1][ks]);                \
    a2 = *(const bf16x8*)(smemc + (bufc)*32768 + offA[2][ks]);                \
    a3 = *(const bf16x8*)(smemc + (bufc)*32768 + offA[3][ks]);                \
    b0 = *(const bf16x8*)(smemc + (bufc)*32768 + 16384 + offB[0][ks]);        \
    b1 = *(const bf16x8*)(smemc + (bufc)*32768 + 16384 + offB[1][ks]);

#define MFMA8 do {                                                                  \
    acc[0][0] = __builtin_amdgcn_mfma_f32_32x32x16_bf16(a0, b0, acc[0][0], 0,0,0);  \
    acc[1][0] = __builtin_amdgcn_mfma_f32_32x32x16_bf16(a1, b0, acc[1][0], 0,0,0);  \
    acc[2][0] = __builtin_amdgcn_mfma_f32_32x32x16_bf16(a2, b0, acc[2][0], 0,0,0);  \
    acc[3][0] = __builtin_amdgcn_mfma_f32_32x32x16_bf16(a3, b0, acc[3][0], 0,0,0);  \
    acc[0][1] = __builtin_amdgcn_mfma_f32_32x32x16_bf16(a0, b1, acc[0][1], 0,0,0);  \
    acc[1][1] = __builtin_amdgcn_mfma_f32_32x32x16_bf16(a1, b1, acc[1][1], 0,0,0);  \
    acc[2][1] = __builtin_amdgcn_mfma_f32_32x32x16_bf16(a2, b1, acc[2][1], 0,0,0);  \
    acc[3][1] = __builtin_amdgcn_mfma_f32_32x32x16_bf16(a3, b1, acc[3][1], 0,0,0);  \
} while (0)

#define BARRIER_IN do {                                     \
    __builtin_amdgcn_sched_barrier(0);                      \
    __builtin_amdgcn_s_barrier();                           \
    asm volatile("s_waitcnt lgkmcnt(0)" ::: "memory");      \
    __builtin_amdgcn_sched_barrier(0);                      \
    __builtin_amdgcn_s_setprio(1);                          \
} while (0)

#define BARRIER_OUT do {                                    \
    __builtin_amdgcn_s_setprio(0);                          \
    __builtin_amdgcn_sched_barrier(0);                      \
    __builtin_amdgcn_s_barrier();                           \
    __builtin_amdgcn_sched_barrier(0);                      \
} while (0)

#define WAIT4 asm volatile("s_waitcnt vmcnt(4)" ::: "memory")
#define WAIT0 asm volatile("s_waitcnt vmcnt(0)" ::: "memory")
#define WNONE do {} while (0)

// One K-tile, one barrier-pair. bufc = t%3 (compile-time), bufs = (t+2)%3.
#define KTILE3(t, bufc, bufs, SG, WT) do {                          \
    LOADK(0, bufc);                                                 \
    if (SG) { STAGE(Abase, ((t)+2)*32, bufs, 0);                    \
              STAGE(Bbase, ((t)+2)*32, bufs, 1); }                  \
    BARRIER_IN;                                                     \
    MFMA8;                                                          \
    LOADK(1, bufc);                                                 \
    asm volatile("s_waitcnt lgkmcnt(0)" ::: "memory");              \
    __builtin_amdgcn_sched_barrier(0);                              \
    MFMA8;                                                          \
    WT;                                                             \
    BARRIER_OUT;                                                    \
} while (0)

__global__ __launch_bounds__(512, 2) void gemm3_kernel(const __hip_bfloat16* __restrict__ A,
                                                       const __hip_bfloat16* __restrict__ Wb,
                                                       const float* __restrict__ bias,
                                                       float* __restrict__ C) {
    __shared__ __align__(16) __hip_bfloat16 smem[3][2][8192];  // 96 KiB
    char* smemc = (char*)&smem[0][0][0];

    const int tid  = threadIdx.x;
    const int lane = tid & 63;
    const int wid  = tid >> 6;        // 0..7
    const int wr   = wid >> 2;        // 0..1  (M half)
    const int wc   = wid & 3;         // 0..3  (N quarter)

    // T1: XCD-aware swizzle (nwg=512, 512%8==0 -> bijective).
    const int bid = blockIdx.x;
    const int swz = (bid & 7) * 64 + (bid >> 3);
    const int bn  = swz >> 6;         // 0..7
    const int bm  = swz & 63;         // 0..63

    const __hip_bfloat16* Abase = A  + (size_t)bm * 256 * KDIM;
    const __hip_bfloat16* Bbase = Wb + (size_t)bn * 256 * KDIM;

    // --- staging source offsets (inverse-swizzled global, linear LDS dest) ---
    const int c0  = wid * 64 + lane;          // chunk 0..511
    const int c1  = 512 + wid * 64 + lane;    // chunk 512..1023
    const int cs0 = c0 ^ ((c0 >> 3) & 7);
    const int cs1 = c1 ^ ((c1 >> 3) & 7);
    const int gOff0 = (cs0 >> 2) * KDIM + (cs0 & 3) * 8;   // elements
    const int gOff1 = (cs1 >> 2) * KDIM + (cs1 & 3) * 8;
    const int lOff0 = wid * 1024;                          // bytes (wave-uniform)
    const int lOff1 = 8192 + wid * 1024;

    // --- swizzled ds_read byte offsets (32x32x16 fragment pattern) ---
    // A: row = wr*128 + mf*32 + (lane&31), kbyte = ks*32 + (lane>>5)*16
    // B: row = wc*64  + nf*32 + (lane&31), same kbyte
    const int l31 = lane & 31;
    const int kh  = (lane >> 5) * 16;
    int offA[4][2], offB[2][2];
#pragma unroll
    for (int mf = 0; mf < 4; ++mf)
#pragma unroll
        for (int ks = 0; ks < 2; ++ks) {
            int a = (wr * 128 + mf * 32 + l31) * 64 + ks * 32 + kh;
            offA[mf][ks] = a ^ (((a >> 7) & 7) << 4);
        }
#pragma unroll
    for (int nf = 0; nf < 2; ++nf)
#pragma unroll
        for (int ks = 0; ks < 2; ++ks) {
            int a = (wc * 64 + nf * 32 + l31) * 64 + ks * 32 + kh;
            offB[nf][ks] = a ^ (((a >> 7) & 7) << 4);
        }

    f32x16 acc[4][2];
#pragma unroll
    for (int mf = 0; mf < 4; ++mf)
#pragma unroll
        for (int nf = 0; nf < 2; ++nf)
#pragma unroll
            for (int r = 0; r < 16; ++r)
                acc[mf][nf][r] = 0.f;

    bf16x8 a0, a1, a2, a3, b0, b1;

    // --- prologue: stage tile0 -> buf0, tile1 -> buf1 (8 loads/wave) ---
    STAGE(Abase,  0, 0, 0);
    STAGE(Bbase,  0, 0, 1);
    STAGE(Abase, 32, 1, 0);
    STAGE(Bbase, 32, 1, 1);
    WAIT4;                    // tile0 landed; tile1's 4 may stay in flight
    __builtin_amdgcn_sched_barrier(0);
    __builtin_amdgcn_s_barrier();
    __builtin_amdgcn_sched_barrier(0);

    // --- main loop: KDIM/32 = 64 K-tiles, buf = t%3 ---
    for (int t = 0; t < 60; t += 3) {
        KTILE3(t,     0, 2, 1, WAIT4);
        KTILE3(t + 1, 1, 0, 1, WAIT4);
        KTILE3(t + 2, 2, 1, 1, WAIT4);
    }
    KTILE3(60, 0, 2, 1, WAIT4);   // stages t62
    KTILE3(61, 1, 0, 1, WAIT4);   // stages t63
    KTILE3(62, 2, 1, 0, WAIT0);   // drain: t63 landed
    KTILE3(63, 0, 1, 0, WNONE);

    // --- epilogue: 32x32 C/D layout col=lane&31, row=(reg&3)+8*(reg>>2)+4*(lane>>5) ---
    const int rupper = 4 * (lane >> 5);
#pragma unroll
    for (int nf = 0; nf < 2; ++nf) {
        const int cg = bn * 256 + wc * 64 + nf * 32 + l31;
        const float bv = bias[cg];
#pragma unroll
        for (int mf = 0; mf < 4; ++mf) {
            const size_t rb = (size_t)bm * 256 + wr * 128 + mf * 32 + rupper;
#pragma unroll
            for (int reg = 0; reg < 16; ++reg) {
                const int row = (reg & 3) + 8 * (reg >> 2);
                C[(rb + row) * NDIM + cg] = acc[mf][nf][reg] + bv;
            }
        }
    }
}

// ---------------------------------------------------------------------------
// Fallback: naive fused fp32 GEMM (only if workspace too small).
// ---------------------------------------------------------------------------
__global__ void naive_kernel(const float* __restrict__ x,
                             const float* __restrict__ leaf,
                             const float* __restrict__ W,
                             const float* __restrict__ bias,
                             float* __restrict__ out) {
    long idx = (long)blockIdx.x * blockDim.x + threadIdx.x;
    if (idx >= (long)MROWS * NDIM) return;
    int  o = (int)(idx % NDIM);
    long m = idx / NDIM;
    int o2 = o / 169, o1 = (o / 13) % 13, o0 = o % 13;
    float acc = 0.f;
    for (int i = 0; i < KDIM; ++i) {
        int i2 = i / 169, i1 = (i / 13) % 13, i0 = i % 13;
        float d = 0.f;
#pragma unroll
        for (int r = 0; r < RANKD; ++r)
            d += leaf[( r     * LEAFD + o2) * LEAFD + i2]
               * leaf[((4 + r) * LEAFD + o1) * LEAFD + i1]
               * leaf[((8 + r) * LEAFD + o0) * LEAFD + i0];
        acc += x[m * KDIM + i] * (W[(long)o * KDIM + i] + d);
    }
    out[idx] = acc + bias[o];
}

// ---------------------------------------------------------------------------
extern "C" void kernel_launch(void* const* d_in, const int* in_sizes, int n_in,
                              void* d_out, int out_size, void* d_ws, size_t ws_size,
                              hipStream_t stream) {
    const float* x      = (const float*)d_in[0];
    const float* leaf   = (const float*)d_in[1];
    const float* weight = (const float*)d_in[2];
    const float* bias   = (const float*)d_in[3];
    float* out = (float*)d_out;

    const size_t needA = (size_t)MROWS * KDIM * sizeof(__hip_bfloat16);  // 64 MiB
    const size_t needW = (size_t)NDIM  * KDIM * sizeof(__hip_bfloat16);  // 8 MiB

    if (ws_size >= needA + needW) {
        __hip_bfloat16* xb = (__hip_bfloat16*)d_ws;
        __hip_bfloat16* wb = (__hip_bfloat16*)((char*)d_ws + needA);
        build_w_kernel<<<(NDIM * KDIM + 255) / 256, 256, 0, stream>>>(weight, leaf, wb);
        cvt_kernel<<<2048, 256, 0, stream>>>(x, xb, MROWS * KDIM);
        gemm3_kernel<<<(MROWS / 256) * (NDIM / 256), 512, 0, stream>>>(xb, wb, bias, out);
    } else {
        long total = (long)MROWS * NDIM;
        naive_kernel<<<(int)((total + 255) / 256), 256, 0, stream>>>(x, leaf, weight, bias, out);
    }
}